// Round 3
// baseline (1267.808 us; speedup 1.0000x reference)
//
#include <hip/hip_runtime.h>
#include <stdint.h>
#include <stddef.h>

#define TSTEPS 2048
#define BATCH  512
#define IDIM   28
#define NDIM   256

typedef __attribute__((ext_vector_type(4))) float f32x4;
typedef __attribute__((ext_vector_type(8))) short short8;

#define MFMA __builtin_amdgcn_mfma_f32_16x16x32_bf16

// pack two f32x4 into 8 bf16 (RNE) slots: v[0..3]=a, v[4..7]=b
__device__ __forceinline__ short8 pack2(f32x4 a, f32x4 b) {
  union { uint32_t u[4]; short8 s; } r;
  asm("v_cvt_pk_bf16_f32 %0, %1, %2" : "=v"(r.u[0]) : "v"(a[0]), "v"(a[1]));
  asm("v_cvt_pk_bf16_f32 %0, %1, %2" : "=v"(r.u[1]) : "v"(a[2]), "v"(a[3]));
  asm("v_cvt_pk_bf16_f32 %0, %1, %2" : "=v"(r.u[2]) : "v"(b[0]), "v"(b[1]));
  asm("v_cvt_pk_bf16_f32 %0, %1, %2" : "=v"(r.u[3]) : "v"(b[2]), "v"(b[3]));
  return r.s;
}

// LDS-only barrier: wait LDS ops, raw s_barrier; in-flight global prefetch
// loads stay outstanding (counted vmcnt inserted by compiler at first use).
#define LDS_BARRIER()                                       \
  do {                                                      \
    __asm__ volatile("s_waitcnt lgkmcnt(0)" ::: "memory");  \
    __builtin_amdgcn_s_barrier();                           \
    __asm__ volatile("" ::: "memory");                      \
  } while (0)

// One timestep. P = LDS buffer parity. DLO/DHI hold data[t] (f32) and are
// re-loaded with data[t+4] (distance-4 register prefetch).
// Wave owns rows [64w,64w+64) = global k-slots 2w,2w+1 (register slots 0,1
// after per-wave rotation). Foreign slots kt'=2..7 come from LDS (Bf0..Bf5).
#define RNN_STEP(P, DLO, DHI, tcur)                                           \
  {                                                                           \
    const short8* rb = (const short8*)(&ldsf[(P)][0][0][0]);                  \
    short8 Bf0 = rb[rdOff0], Bf1 = rb[rdOff1], Bf2 = rb[rdOff2];              \
    short8 Bf3 = rb[rdOff3], Bf4 = rb[rdOff4], Bf5 = rb[rdOff5];              \
    short8 Bx = pack2(DLO, DHI);                                              \
    {                                                                         \
      int tt = (tcur) + 4; tt = (tt > TSTEPS - 1) ? (TSTEPS - 1) : tt;        \
      const float* rp = dptr + (size_t)tt * (BATCH * IDIM);                   \
      DLO = *(const f32x4*)rp;                                                \
      if (g < 3) DHI = *(const f32x4*)(rp + 16);                              \
    }                                                                         \
    f32x4 aA0, aA1, aA2, aA3;                                                 \
    _Pragma("unroll")                                                         \
    for (int r = 0; r < 4; ++r) {                                             \
      aA0[r] = __builtin_fmaf(0.5f, hc0[r], cst0[r]);                         \
      aA1[r] = __builtin_fmaf(0.5f, hc1[r], cst1[r]);                         \
      aA2[r] = __builtin_fmaf(0.5f, hc2[r], cst2[r]);                         \
      aA3[r] = __builtin_fmaf(0.5f, hc3[r], cst3[r]);                         \
    }                                                                         \
    /* LDS-free MFMAs first: own k-slots (regs) + input projection */         \
    aA0 = MFMA(A_hh[0][0], Bown0, aA0, 0, 0, 0);                              \
    aA1 = MFMA(A_hh[1][0], Bown0, aA1, 0, 0, 0);                              \
    aA2 = MFMA(A_hh[2][0], Bown0, aA2, 0, 0, 0);                              \
    aA3 = MFMA(A_hh[3][0], Bown0, aA3, 0, 0, 0);                              \
    aA0 = MFMA(A_hh[0][1], Bown1, aA0, 0, 0, 0);                              \
    aA1 = MFMA(A_hh[1][1], Bown1, aA1, 0, 0, 0);                              \
    aA2 = MFMA(A_hh[2][1], Bown1, aA2, 0, 0, 0);                              \
    aA3 = MFMA(A_hh[3][1], Bown1, aA3, 0, 0, 0);                              \
    f32x4 z4 = {0.f, 0.f, 0.f, 0.f};                                          \
    f32x4 aB0 = MFMA(A_in[0], Bx, z4, 0, 0, 0);                               \
    f32x4 aB1 = MFMA(A_in[1], Bx, z4, 0, 0, 0);                               \
    f32x4 aB2 = MFMA(A_in[2], Bx, z4, 0, 0, 0);                               \
    f32x4 aB3 = MFMA(A_in[3], Bx, z4, 0, 0, 0);                               \
    /* foreign k-slots in LDS arrival order */                                \
    aA0 = MFMA(A_hh[0][2], Bf0, aA0, 0, 0, 0);                                \
    aA1 = MFMA(A_hh[1][2], Bf0, aA1, 0, 0, 0);                                \
    aA2 = MFMA(A_hh[2][2], Bf0, aA2, 0, 0, 0);                                \
    aA3 = MFMA(A_hh[3][2], Bf0, aA3, 0, 0, 0);                                \
    aA0 = MFMA(A_hh[0][3], Bf1, aA0, 0, 0, 0);                                \
    aA1 = MFMA(A_hh[1][3], Bf1, aA1, 0, 0, 0);                                \
    aA2 = MFMA(A_hh[2][3], Bf1, aA2, 0, 0, 0);                                \
    aA3 = MFMA(A_hh[3][3], Bf1, aA3, 0, 0, 0);                                \
    aB0 = MFMA(A_hh[0][4], Bf2, aB0, 0, 0, 0);                                \
    aB1 = MFMA(A_hh[1][4], Bf2, aB1, 0, 0, 0);                                \
    aB2 = MFMA(A_hh[2][4], Bf2, aB2, 0, 0, 0);                                \
    aB3 = MFMA(A_hh[3][4], Bf2, aB3, 0, 0, 0);                                \
    aB0 = MFMA(A_hh[0][5], Bf3, aB0, 0, 0, 0);                                \
    aB1 = MFMA(A_hh[1][5], Bf3, aB1, 0, 0, 0);                                \
    aB2 = MFMA(A_hh[2][5], Bf3, aB2, 0, 0, 0);                                \
    aB3 = MFMA(A_hh[3][5], Bf3, aB3, 0, 0, 0);                                \
    aB0 = MFMA(A_hh[0][6], Bf4, aB0, 0, 0, 0);                                \
    aB1 = MFMA(A_hh[1][6], Bf4, aB1, 0, 0, 0);                                \
    aB2 = MFMA(A_hh[2][6], Bf4, aB2, 0, 0, 0);                                \
    aB3 = MFMA(A_hh[3][6], Bf4, aB3, 0, 0, 0);                                \
    aB0 = MFMA(A_hh[0][7], Bf5, aB0, 0, 0, 0);                                \
    aB1 = MFMA(A_hh[1][7], Bf5, aB1, 0, 0, 0);                                \
    aB2 = MFMA(A_hh[2][7], Bf5, aB2, 0, 0, 0);                                \
    aB3 = MFMA(A_hh[3][7], Bf5, aB3, 0, 0, 0);                                \
    _Pragma("unroll")                                                         \
    for (int r = 0; r < 4; ++r) {                                             \
      float p0 = aA0[r] + aB0[r]; hc0[r] = __builtin_fmaxf(p0, 0.01f * p0);   \
      float p1 = aA1[r] + aB1[r]; hc1[r] = __builtin_fmaxf(p1, 0.01f * p1);   \
      float p2 = aA2[r] + aB2[r]; hc2[r] = __builtin_fmaxf(p2, 0.01f * p2);   \
      float p3 = aA3[r] + aB3[r]; hc3[r] = __builtin_fmaxf(p3, 0.01f * p3);   \
    }                                                                         \
    Bown0 = pack2(hc0, hc1);                                                  \
    Bown1 = pack2(hc2, hc3);                                                  \
    short8* wb = (short8*)(&ldsf[(P) ^ 1][0][0][0]);                          \
    wb[wrOff0] = Bown0;                                                       \
    wb[wrOff1] = Bown1;                                                       \
    LDS_BARRIER();                                                            \
  }

__global__ __launch_bounds__(256, 1)
void rnn_fused(const float* __restrict__ data,   // [T][B][I]
               const float* __restrict__ hier,   // [B][N]
               const float* __restrict__ h0,     // [B][N]
               const float* __restrict__ W_in,   // [N][I]
               const float* __restrict__ b_in,   // [N]
               const float* __restrict__ W_hh,   // [N][N]
               const float* __restrict__ b_hh,   // [N]
               const float* __restrict__ W_ff,   // [N][N]
               const float* __restrict__ b_ff,   // [N]
               const float* __restrict__ W_fc,   // [2][N]
               const float* __restrict__ b_fc,   // [2]
               float* __restrict__ out)          // [B][2]
{
  // frag store: [parity][global k-slot 0..7][64 lanes][8 bf16] = 16 KiB
  __shared__ __attribute__((aligned(16))) short ldsf[2][8][64][8];
  __shared__ float ldsh[16][264];  // final h scratch (padded)

  const int tid  = threadIdx.x;
  const int wave = tid >> 6;    // 0..3; owns out-neuron rows [64w, 64w+64)
  const int lane = tid & 63;
  const int g    = lane >> 4;   // k-group 0..3
  const int c    = lane & 15;   // batch col (B/C roles) or M-row (A role)
  const int b0   = blockIdx.x * 16;

  // LDS frag offsets (units of short8 = 16 B). Own global slots: 2w, 2w+1.
  const int wrOff0 = (2 * wave) * 64 + lane;
  const int wrOff1 = (2 * wave + 1) * 64 + lane;
  // foreign slots, register slot kt' = j+2 -> global slot (2w+2+j)&7
  const int rdOff0 = (((2 * wave + 2) & 7)) * 64 + lane;
  const int rdOff1 = (((2 * wave + 3) & 7)) * 64 + lane;
  const int rdOff2 = (((2 * wave + 4) & 7)) * 64 + lane;
  const int rdOff3 = (((2 * wave + 5) & 7)) * 64 + lane;
  const int rdOff4 = (((2 * wave + 6) & 7)) * 64 + lane;
  const int rdOff5 = (((2 * wave + 7) & 7)) * 64 + lane;

  // ---- prologue: cst = 0.5*(b_hh + b_in + b_ff + hier @ W_ff^T) via MFMA ----
  f32x4 cst0 = {0.f,0.f,0.f,0.f}, cst1 = {0.f,0.f,0.f,0.f};
  f32x4 cst2 = {0.f,0.f,0.f,0.f}, cst3 = {0.f,0.f,0.f,0.f};
  {
    const float* hp = hier + (size_t)(b0 + c) * NDIM;
    const float* w0 = W_ff + (size_t)(64 * wave + 16 * 0 + c) * NDIM;
    const float* w1 = W_ff + (size_t)(64 * wave + 16 * 1 + c) * NDIM;
    const float* w2 = W_ff + (size_t)(64 * wave + 16 * 2 + c) * NDIM;
    const float* w3 = W_ff + (size_t)(64 * wave + 16 * 3 + c) * NDIM;
#pragma unroll
    for (int kt = 0; kt < 8; ++kt) {
      const int o = 32 * kt + 4 * g;
      short8 bh = pack2(*(const f32x4*)(hp + o), *(const f32x4*)(hp + o + 16));
      cst0 = MFMA(pack2(*(const f32x4*)(w0 + o), *(const f32x4*)(w0 + o + 16)), bh, cst0, 0, 0, 0);
      cst1 = MFMA(pack2(*(const f32x4*)(w1 + o), *(const f32x4*)(w1 + o + 16)), bh, cst1, 0, 0, 0);
      cst2 = MFMA(pack2(*(const f32x4*)(w2 + o), *(const f32x4*)(w2 + o + 16)), bh, cst2, 0, 0, 0);
      cst3 = MFMA(pack2(*(const f32x4*)(w3 + o), *(const f32x4*)(w3 + o + 16)), bh, cst3, 0, 0, 0);
    }
  }
#pragma unroll
  for (int r = 0; r < 4; ++r) {
    const int n0 = 64 * wave + 4 * g + r;
    cst0[r] = 0.5f * (cst0[r] + b_hh[n0]      + b_in[n0]      + b_ff[n0]);
    cst1[r] = 0.5f * (cst1[r] + b_hh[n0 + 16] + b_in[n0 + 16] + b_ff[n0 + 16]);
    cst2[r] = 0.5f * (cst2[r] + b_hh[n0 + 32] + b_in[n0 + 32] + b_ff[n0 + 32]);
    cst3[r] = 0.5f * (cst3[r] + b_hh[n0 + 48] + b_in[n0 + 48] + b_ff[n0 + 48]);
  }

  // ---- A-frags: 0.5*W_hh (diag zeroed), rotated k-slots; 0.5*W_in ----
  short8 A_hh[4][8];
  short8 A_in[4];
#pragma unroll
  for (int i = 0; i < 4; ++i) {
    const int row = 64 * wave + 16 * i + c;
    const float* wr = W_hh + (size_t)row * NDIM;
#pragma unroll
    for (int ktp = 0; ktp < 8; ++ktp) {
      const int ktg = (ktp + 2 * wave) & 7;   // global k-tile for reg slot ktp
      f32x4 lo = *(const f32x4*)(wr + 32 * ktg + 4 * g);
      f32x4 hi = *(const f32x4*)(wr + 32 * ktg + 16 + 4 * g);
#pragma unroll
      for (int j = 0; j < 4; ++j) {
        const int kl = 32 * ktg + 4 * g + j, kh = kl + 16;
        lo[j] = (kl == row) ? 0.f : 0.5f * lo[j];
        hi[j] = (kh == row) ? 0.f : 0.5f * hi[j];
      }
      A_hh[i][ktp] = pack2(lo, hi);
    }
    const float* p = W_in + (size_t)row * IDIM;
    f32x4 lo = *(const f32x4*)(p + 4 * g);
    f32x4 hi = {0.f, 0.f, 0.f, 0.f};
    if (g < 3) hi = *(const f32x4*)(p + 16 + 4 * g);
#pragma unroll
    for (int j = 0; j < 4; ++j) { lo[j] *= 0.5f; hi[j] *= 0.5f; }
    A_in[i] = pack2(lo, hi);
  }

  // ---- h0: f32 state (C layout) + own bf16 frags into buf 0 ----
  f32x4 hc0, hc1, hc2, hc3;
  short8 Bown0, Bown1;
  {
    const float* hp = h0 + (size_t)(b0 + c) * NDIM + 64 * wave + 4 * g;
    hc0 = *(const f32x4*)(hp + 0);
    hc1 = *(const f32x4*)(hp + 16);
    hc2 = *(const f32x4*)(hp + 32);
    hc3 = *(const f32x4*)(hp + 48);
    Bown0 = pack2(hc0, hc1);
    Bown1 = pack2(hc2, hc3);
    short8* wb = (short8*)(&ldsf[0][0][0][0]);
    wb[wrOff0] = Bown0;
    wb[wrOff1] = Bown1;
  }

  // ---- data register prefetch for t=0..3 (distance-4 pipeline) ----
  const float* dptr = data + (size_t)(b0 + c) * IDIM + 4 * g;
  f32x4 dlo0, dlo1, dlo2, dlo3;
  f32x4 dhi0 = {0.f,0.f,0.f,0.f}, dhi1 = {0.f,0.f,0.f,0.f};
  f32x4 dhi2 = {0.f,0.f,0.f,0.f}, dhi3 = {0.f,0.f,0.f,0.f};
  dlo0 = *(const f32x4*)dptr;
  dlo1 = *(const f32x4*)(dptr + (size_t)1 * BATCH * IDIM);
  dlo2 = *(const f32x4*)(dptr + (size_t)2 * BATCH * IDIM);
  dlo3 = *(const f32x4*)(dptr + (size_t)3 * BATCH * IDIM);
  if (g < 3) {
    dhi0 = *(const f32x4*)(dptr + 16);
    dhi1 = *(const f32x4*)(dptr + (size_t)1 * BATCH * IDIM + 16);
    dhi2 = *(const f32x4*)(dptr + (size_t)2 * BATCH * IDIM + 16);
    dhi3 = *(const f32x4*)(dptr + (size_t)3 * BATCH * IDIM + 16);
  }

  __syncthreads();  // initial frags visible

  // ---- time loop, unrolled x4: compile-time parities + 4 prefetch slots ----
  for (int t = 0; t < TSTEPS; t += 4) {
    RNN_STEP(0, dlo0, dhi0, t)
    RNN_STEP(1, dlo1, dhi1, t + 1)
    RNN_STEP(0, dlo2, dhi2, t + 2)
    RNN_STEP(1, dlo3, dhi3, t + 3)
  }

  // ---- readout: out = hT @ W_fc^T + b_fc ----
  *(f32x4*)(&ldsh[c][64 * wave + 4 * g])      = hc0;
  *(f32x4*)(&ldsh[c][64 * wave + 16 + 4 * g]) = hc1;
  *(f32x4*)(&ldsh[c][64 * wave + 32 + 4 * g]) = hc2;
  *(f32x4*)(&ldsh[c][64 * wave + 48 + 4 * g]) = hc3;
  __syncthreads();
  if (tid < 32) {
    int b = tid >> 1, cls = tid & 1;
    float s = b_fc[cls];
    const float* wf = W_fc + (size_t)cls * NDIM;
#pragma unroll 8
    for (int n = 0; n < NDIM; ++n) s += ldsh[b][n] * wf[n];
    out[(size_t)(b0 + b) * 2 + cls] = s;
  }
}

extern "C" void kernel_launch(void* const* d_in, const int* in_sizes, int n_in,
                              void* d_out, int out_size, void* d_ws, size_t ws_size,
                              hipStream_t stream) {
  const float* data = (const float*)d_in[0];
  const float* hier = (const float*)d_in[1];
  const float* h0   = (const float*)d_in[2];
  const float* W_in = (const float*)d_in[3];
  const float* b_in = (const float*)d_in[4];
  const float* W_hh = (const float*)d_in[5];
  const float* b_hh = (const float*)d_in[6];
  const float* W_ff = (const float*)d_in[7];
  const float* b_ff = (const float*)d_in[8];
  const float* W_fc = (const float*)d_in[9];
  const float* b_fc = (const float*)d_in[10];
  rnn_fused<<<dim3(BATCH / 16), dim3(256), 0, stream>>>(
      data, hier, h0, W_in, b_in, W_hh, b_hh, W_ff, b_ff, W_fc, b_fc,
      (float*)d_out);
}

// Round 4
// 1049.264 us; speedup vs baseline: 1.2083x; 1.2083x over previous
//
#include <hip/hip_runtime.h>
#include <stdint.h>
#include <stddef.h>

#define TSTEPS 2048
#define BATCH  512
#define IDIM   28
#define NDIM   256

typedef __attribute__((ext_vector_type(4))) float f32x4;
typedef __attribute__((ext_vector_type(8))) short short8;

#define MFMA __builtin_amdgcn_mfma_f32_16x16x32_bf16

// pack two f32x4 into 8 bf16 (RNE) slots: v[0..3]=a, v[4..7]=b
__device__ __forceinline__ short8 pack2(f32x4 a, f32x4 b) {
  union { uint32_t u[4]; short8 s; } r;
  asm("v_cvt_pk_bf16_f32 %0, %1, %2" : "=v"(r.u[0]) : "v"(a[0]), "v"(a[1]));
  asm("v_cvt_pk_bf16_f32 %0, %1, %2" : "=v"(r.u[1]) : "v"(a[2]), "v"(a[3]));
  asm("v_cvt_pk_bf16_f32 %0, %1, %2" : "=v"(r.u[2]) : "v"(b[0]), "v"(b[1]));
  asm("v_cvt_pk_bf16_f32 %0, %1, %2" : "=v"(r.u[3]) : "v"(b[2]), "v"(b[3]));
  return r.s;
}

// LDS-only barrier: wait LDS ops, raw s_barrier; in-flight global prefetch
// loads stay outstanding (counted vmcnt inserted by compiler at first use).
#define LDS_BARRIER()                                       \
  do {                                                      \
    __asm__ volatile("s_waitcnt lgkmcnt(0)" ::: "memory");  \
    __builtin_amdgcn_s_barrier();                           \
    __asm__ volatile("" ::: "memory");                      \
  } while (0)

// One timestep. P = parity (t&1). DLO/DHI hold data[t]; when PF, reload with
// data[t+4] from linear pointer dpf (strength-reduced, no clamp).
// Wave owns k-slot `wave` (rows 32w..32w+31): own B-frag stays in registers
// (Bown); 7 foreign slots j=1..7 -> global slot (w+j)&7 read from LDS.
#define RNN_STEP(P, DLO, DHI, PF)                                             \
  {                                                                           \
    const short8* rb = (const short8*)(&ldsf[(P)][0][0][0]);                  \
    short8 Bf1 = rb[rd1], Bf2 = rb[rd2], Bf3 = rb[rd3], Bf4 = rb[rd4];        \
    short8 Bf5 = rb[rd5], Bf6 = rb[rd6], Bf7 = rb[rd7];                       \
    short8 Bx = pack2(DLO, DHI);                                              \
    if (PF) {                                                                 \
      DLO = *(const f32x4*)dpf;                                               \
      DHI = *(const f32x4*)(dpf + hiOff);                                     \
      dpf += BATCH * IDIM;                                                    \
    }                                                                         \
    f32x4 acc0, acc1;                                                         \
    _Pragma("unroll")                                                         \
    for (int r = 0; r < 4; ++r) {                                             \
      acc0[r] = __builtin_fmaf(0.5f, hc0[r], cst0[r]);                        \
      acc1[r] = __builtin_fmaf(0.5f, hc1[r], cst1[r]);                        \
    }                                                                         \
    __builtin_amdgcn_s_setprio(1);                                            \
    acc0 = MFMA(A_hh[0][0], Bown, acc0, 0, 0, 0);                             \
    acc1 = MFMA(A_hh[1][0], Bown, acc1, 0, 0, 0);                             \
    acc0 = MFMA(A_in[0], Bx, acc0, 0, 0, 0);                                  \
    acc1 = MFMA(A_in[1], Bx, acc1, 0, 0, 0);                                  \
    acc0 = MFMA(A_hh[0][1], Bf1, acc0, 0, 0, 0);                              \
    acc1 = MFMA(A_hh[1][1], Bf1, acc1, 0, 0, 0);                              \
    acc0 = MFMA(A_hh[0][2], Bf2, acc0, 0, 0, 0);                              \
    acc1 = MFMA(A_hh[1][2], Bf2, acc1, 0, 0, 0);                              \
    acc0 = MFMA(A_hh[0][3], Bf3, acc0, 0, 0, 0);                              \
    acc1 = MFMA(A_hh[1][3], Bf3, acc1, 0, 0, 0);                              \
    acc0 = MFMA(A_hh[0][4], Bf4, acc0, 0, 0, 0);                              \
    acc1 = MFMA(A_hh[1][4], Bf4, acc1, 0, 0, 0);                              \
    acc0 = MFMA(A_hh[0][5], Bf5, acc0, 0, 0, 0);                              \
    acc1 = MFMA(A_hh[1][5], Bf5, acc1, 0, 0, 0);                              \
    acc0 = MFMA(A_hh[0][6], Bf6, acc0, 0, 0, 0);                              \
    acc1 = MFMA(A_hh[1][6], Bf6, acc1, 0, 0, 0);                              \
    acc0 = MFMA(A_hh[0][7], Bf7, acc0, 0, 0, 0);                              \
    acc1 = MFMA(A_hh[1][7], Bf7, acc1, 0, 0, 0);                              \
    __builtin_amdgcn_s_setprio(0);                                            \
    _Pragma("unroll")                                                         \
    for (int r = 0; r < 4; ++r) {                                             \
      float p0 = acc0[r]; hc0[r] = __builtin_fmaxf(p0, 0.01f * p0);           \
      float p1 = acc1[r]; hc1[r] = __builtin_fmaxf(p1, 0.01f * p1);           \
    }                                                                         \
    Bown = pack2(hc0, hc1);                                                   \
    ((short8*)(&ldsf[(P) ^ 1][0][0][0]))[wr] = Bown;                          \
    LDS_BARRIER();                                                            \
  }

__global__ __launch_bounds__(512, 2)
void rnn_fused(const float* __restrict__ data,   // [T][B][I]
               const float* __restrict__ hier,   // [B][N]
               const float* __restrict__ h0,     // [B][N]
               const float* __restrict__ W_in,   // [N][I]
               const float* __restrict__ b_in,   // [N]
               const float* __restrict__ W_hh,   // [N][N]
               const float* __restrict__ b_hh,   // [N]
               const float* __restrict__ W_ff,   // [N][N]
               const float* __restrict__ b_ff,   // [N]
               const float* __restrict__ W_fc,   // [2][N]
               const float* __restrict__ b_fc,   // [2]
               float* __restrict__ out)          // [B][2]
{
  // frag store: [parity][global k-slot 0..7][64 lanes][8 bf16] = 16 KiB
  __shared__ __attribute__((aligned(16))) short ldsf[2][8][64][8];
  __shared__ float ldsh[16][264];  // final h scratch (padded)

  const int tid  = threadIdx.x;
  const int wave = tid >> 6;    // 0..7; owns rows [32w,32w+32) = k-slot w
  const int lane = tid & 63;
  const int g    = lane >> 4;   // k-group 0..3
  const int c    = lane & 15;   // batch col (B/C roles) or M-row (A role)
  const int b0   = blockIdx.x * 16;

  const int m0 = 32 * wave + c;   // A-tile row, tile 0
  const int m1 = m0 + 16;         // tile 1

  // LDS indices (short8 units). Own slot: wave. Foreign j -> (wave+j)&7.
  const int wr  = wave * 64 + lane;
  const int rd1 = ((wave + 1) & 7) * 64 + lane;
  const int rd2 = ((wave + 2) & 7) * 64 + lane;
  const int rd3 = ((wave + 3) & 7) * 64 + lane;
  const int rd4 = ((wave + 4) & 7) * 64 + lane;
  const int rd5 = ((wave + 5) & 7) * 64 + lane;
  const int rd6 = ((wave + 6) & 7) * 64 + lane;
  const int rd7 = ((wave + 7) & 7) * 64 + lane;

  // ---- prologue: cst = 0.5*(b_hh + b_in + b_ff + hier @ W_ff^T) via MFMA ----
  f32x4 cst0 = {0.f,0.f,0.f,0.f}, cst1 = {0.f,0.f,0.f,0.f};
  {
    const float* hp = hier + (size_t)(b0 + c) * NDIM + 4 * g;
    const float* w0 = W_ff + (size_t)m0 * NDIM + 4 * g;
    const float* w1 = W_ff + (size_t)m1 * NDIM + 4 * g;
#pragma unroll
    for (int kt = 0; kt < 8; ++kt) {
      short8 bh  = pack2(*(const f32x4*)(hp + kt * 32), *(const f32x4*)(hp + kt * 32 + 16));
      short8 af0 = pack2(*(const f32x4*)(w0 + kt * 32), *(const f32x4*)(w0 + kt * 32 + 16));
      short8 af1 = pack2(*(const f32x4*)(w1 + kt * 32), *(const f32x4*)(w1 + kt * 32 + 16));
      cst0 = MFMA(af0, bh, cst0, 0, 0, 0);
      cst1 = MFMA(af1, bh, cst1, 0, 0, 0);
    }
  }
#pragma unroll
  for (int r = 0; r < 4; ++r) {
    const int n0 = 32 * wave + 4 * g + r;
    cst0[r] = 0.5f * (cst0[r] + b_hh[n0]      + b_in[n0]      + b_ff[n0]);
    cst1[r] = 0.5f * (cst1[r] + b_hh[n0 + 16] + b_in[n0 + 16] + b_ff[n0 + 16]);
  }

  // ---- A-frags: 0.5*W_hh (diag zeroed), k-slots rotated so reg slot j
  //      is global slot (wave+j)&7 (slot 0 = own); 0.5*W_in (I=28 pad 32) ----
  short8 A_hh[2][8];
  short8 A_in[2];
#pragma unroll
  for (int i = 0; i < 2; ++i) {
    const int row = 32 * wave + 16 * i + c;
    const float* wrow = W_hh + (size_t)row * NDIM;
#pragma unroll
    for (int j = 0; j < 8; ++j) {
      const int ktg = (wave + j) & 7;
      f32x4 lo = *(const f32x4*)(wrow + 32 * ktg + 4 * g);
      f32x4 hi = *(const f32x4*)(wrow + 32 * ktg + 16 + 4 * g);
#pragma unroll
      for (int q = 0; q < 4; ++q) {
        const int kl = 32 * ktg + 4 * g + q, kh = kl + 16;
        lo[q] = (kl == row) ? 0.f : 0.5f * lo[q];
        hi[q] = (kh == row) ? 0.f : 0.5f * hi[q];
      }
      A_hh[i][j] = pack2(lo, hi);
    }
    const float* p = W_in + (size_t)row * IDIM;
    f32x4 lo = *(const f32x4*)(p + 4 * g);
    f32x4 hi = {0.f, 0.f, 0.f, 0.f};
    if (g < 3) hi = *(const f32x4*)(p + 16 + 4 * g);  // k rows 28..31 stay 0
#pragma unroll
    for (int q = 0; q < 4; ++q) { lo[q] *= 0.5f; hi[q] *= 0.5f; }
    A_in[i] = pack2(lo, hi);
  }

  // ---- h0: f32 state (C layout) + own bf16 frag into buf 0 ----
  f32x4 hc0, hc1;
  short8 Bown;
  {
    const float* hp = h0 + (size_t)(b0 + c) * NDIM + 32 * wave + 4 * g;
    hc0 = *(const f32x4*)(hp + 0);
    hc1 = *(const f32x4*)(hp + 16);
    Bown = pack2(hc0, hc1);
    ((short8*)(&ldsf[0][0][0][0]))[wr] = Bown;
  }

  // ---- data prefetch t=0..3; branchless hi via per-thread constant offset.
  // g==3's hi reads in-bounds garbage (cols 24..27); annihilated by A zeros.
  const int hiOff = (g < 3) ? 16 : -4;
  const float* dpf = data + (size_t)(b0 + c) * IDIM + 4 * g;
  f32x4 dlo0, dlo1, dlo2, dlo3, dhi0, dhi1, dhi2, dhi3;
  dlo0 = *(const f32x4*)dpf; dhi0 = *(const f32x4*)(dpf + hiOff); dpf += BATCH * IDIM;
  dlo1 = *(const f32x4*)dpf; dhi1 = *(const f32x4*)(dpf + hiOff); dpf += BATCH * IDIM;
  dlo2 = *(const f32x4*)dpf; dhi2 = *(const f32x4*)(dpf + hiOff); dpf += BATCH * IDIM;
  dlo3 = *(const f32x4*)dpf; dhi3 = *(const f32x4*)(dpf + hiOff); dpf += BATCH * IDIM;
  // dpf now points at t=4 (first in-loop prefetch target)

  __syncthreads();  // initial frags visible

  // ---- time loop: 511 macro-iters with prefetch, then 4 peeled steps ----
  for (int t = 0; t < TSTEPS - 4; t += 4) {
    RNN_STEP(0, dlo0, dhi0, 1)
    RNN_STEP(1, dlo1, dhi1, 1)
    RNN_STEP(0, dlo2, dhi2, 1)
    RNN_STEP(1, dlo3, dhi3, 1)
  }
  RNN_STEP(0, dlo0, dhi0, 0)
  RNN_STEP(1, dlo1, dhi1, 0)
  RNN_STEP(0, dlo2, dhi2, 0)
  RNN_STEP(1, dlo3, dhi3, 0)

  // ---- readout: out = hT @ W_fc^T + b_fc ----
  *(f32x4*)(&ldsh[c][32 * wave + 4 * g])      = hc0;
  *(f32x4*)(&ldsh[c][32 * wave + 16 + 4 * g]) = hc1;
  __syncthreads();
  if (tid < 32) {
    int b = tid >> 1, cls = tid & 1;
    float s = b_fc[cls];
    const float* wf = W_fc + (size_t)cls * NDIM;
#pragma unroll 8
    for (int n = 0; n < NDIM; ++n) s += ldsh[b][n] * wf[n];
    out[(size_t)(b0 + b) * 2 + cls] = s;
  }
}

extern "C" void kernel_launch(void* const* d_in, const int* in_sizes, int n_in,
                              void* d_out, int out_size, void* d_ws, size_t ws_size,
                              hipStream_t stream) {
  const float* data = (const float*)d_in[0];
  const float* hier = (const float*)d_in[1];
  const float* h0   = (const float*)d_in[2];
  const float* W_in = (const float*)d_in[3];
  const float* b_in = (const float*)d_in[4];
  const float* W_hh = (const float*)d_in[5];
  const float* b_hh = (const float*)d_in[6];
  const float* W_ff = (const float*)d_in[7];
  const float* b_ff = (const float*)d_in[8];
  const float* W_fc = (const float*)d_in[9];
  const float* b_fc = (const float*)d_in[10];
  rnn_fused<<<dim3(BATCH / 16), dim3(512), 0, stream>>>(
      data, hier, h0, W_in, b_in, W_hh, b_hh, W_ff, b_ff, W_fc, b_fc,
      (float*)d_out);
}

// Round 8
// 919.562 us; speedup vs baseline: 1.3787x; 1.1410x over previous
//
#include <hip/hip_runtime.h>
#include <stdint.h>
#include <stddef.h>

#define TSTEPS 2048
#define BATCH  512
#define IDIM   28
#define NDIM   256

typedef __attribute__((ext_vector_type(4))) float f32x4;
typedef __attribute__((ext_vector_type(8))) short short8;

#define MFMA __builtin_amdgcn_mfma_f32_16x16x32_bf16

// pack two f32x4 into 8 bf16 (RNE) slots: v[0..3]=a, v[4..7]=b
__device__ __forceinline__ short8 pack2(f32x4 a, f32x4 b) {
  union { uint32_t u[4]; short8 s; } r;
  asm("v_cvt_pk_bf16_f32 %0, %1, %2" : "=v"(r.u[0]) : "v"(a[0]), "v"(a[1]));
  asm("v_cvt_pk_bf16_f32 %0, %1, %2" : "=v"(r.u[1]) : "v"(a[2]), "v"(a[3]));
  asm("v_cvt_pk_bf16_f32 %0, %1, %2" : "=v"(r.u[2]) : "v"(b[0]), "v"(b[1]));
  asm("v_cvt_pk_bf16_f32 %0, %1, %2" : "=v"(r.u[3]) : "v"(b[2]), "v"(b[3]));
  return r.s;
}

// LDS-only barrier: wait LDS ops, raw s_barrier; in-flight global prefetch
// loads stay outstanding (counted vmcnt inserted by compiler at first use).
// Proven in the 1020us and 1049us passing kernels.
#define LDS_BARRIER()                                       \
  do {                                                      \
    __asm__ volatile("s_waitcnt lgkmcnt(0)" ::: "memory");  \
    __builtin_amdgcn_s_barrier();                           \
    __asm__ volatile("" ::: "memory");                      \
  } while (0)

// One timestep. P = parity (t&1). DLO/DHI hold data[t]; when PF, reload with
// data[t+4] from linear pointer dpf. Wave owns k-slot `wave` (rows
// 32w..32w+31): own B-frag stays in registers (Bown); 7 foreign slots
// j=1..7 -> global slot (w+j)&7 read from LDS. Split accumulator chains:
// a: own + j1,j2,j3 (init = 0.5h+cst); b: input + j4..j7 (init = 0).
// The two register-ready MFMAs (own, input) issue first to cover Bf latency.
#define RNN_STEP(P, DLO, DHI, PF)                                             \
  {                                                                           \
    const short8* rb = (const short8*)(&ldsf[(P)][0][0][0]);                  \
    short8 Bf1 = rb[rd1], Bf4 = rb[rd4], Bf2 = rb[rd2], Bf5 = rb[rd5];        \
    short8 Bf3 = rb[rd3], Bf6 = rb[rd6], Bf7 = rb[rd7];                       \
    short8 Bx = pack2(DLO, DHI);                                              \
    if (PF) {                                                                 \
      DLO = *(const f32x4*)dpf;                                               \
      DHI = *(const f32x4*)(dpf + hiOff);                                     \
      dpf += BATCH * IDIM;                                                    \
    }                                                                         \
    f32x4 aA0, aA1, aB0, aB1;                                                 \
    _Pragma("unroll")                                                         \
    for (int r = 0; r < 4; ++r) {                                             \
      aA0[r] = __builtin_fmaf(0.5f, hc0[r], cst0[r]);                         \
      aA1[r] = __builtin_fmaf(0.5f, hc1[r], cst1[r]);                         \
    }                                                                         \
    f32x4 z4 = {0.f, 0.f, 0.f, 0.f};                                          \
    /* register-ready first (own slot + input projection) */                  \
    aA0 = MFMA(A_hh[0][0], Bown, aA0, 0, 0, 0);                               \
    aA1 = MFMA(A_hh[1][0], Bown, aA1, 0, 0, 0);                               \
    aB0 = MFMA(A_in[0], Bx, z4, 0, 0, 0);                                     \
    aB1 = MFMA(A_in[1], Bx, z4, 0, 0, 0);                                     \
    /* foreign slots, alternating chains in read order */                     \
    aA0 = MFMA(A_hh[0][1], Bf1, aA0, 0, 0, 0);                                \
    aA1 = MFMA(A_hh[1][1], Bf1, aA1, 0, 0, 0);                                \
    aB0 = MFMA(A_hh[0][4], Bf4, aB0, 0, 0, 0);                                \
    aB1 = MFMA(A_hh[1][4], Bf4, aB1, 0, 0, 0);                                \
    aA0 = MFMA(A_hh[0][2], Bf2, aA0, 0, 0, 0);                                \
    aA1 = MFMA(A_hh[1][2], Bf2, aA1, 0, 0, 0);                                \
    aB0 = MFMA(A_hh[0][5], Bf5, aB0, 0, 0, 0);                                \
    aB1 = MFMA(A_hh[1][5], Bf5, aB1, 0, 0, 0);                                \
    aA0 = MFMA(A_hh[0][3], Bf3, aA0, 0, 0, 0);                                \
    aA1 = MFMA(A_hh[1][3], Bf3, aA1, 0, 0, 0);                                \
    aB0 = MFMA(A_hh[0][6], Bf6, aB0, 0, 0, 0);                                \
    aB1 = MFMA(A_hh[1][6], Bf6, aB1, 0, 0, 0);                                \
    aB0 = MFMA(A_hh[0][7], Bf7, aB0, 0, 0, 0);                                \
    aB1 = MFMA(A_hh[1][7], Bf7, aB1, 0, 0, 0);                                \
    _Pragma("unroll")                                                         \
    for (int r = 0; r < 4; ++r) {                                             \
      float p0 = aA0[r] + aB0[r]; hc0[r] = __builtin_fmaxf(p0, 0.01f * p0);   \
      float p1 = aA1[r] + aB1[r]; hc1[r] = __builtin_fmaxf(p1, 0.01f * p1);   \
    }                                                                         \
    Bown = pack2(hc0, hc1);                                                   \
    ((short8*)(&ldsf[(P) ^ 1][0][0][0]))[wr] = Bown;                          \
    LDS_BARRIER();                                                            \
  }

__global__ __launch_bounds__(512, 2)
void rnn_fused(const float* __restrict__ data,   // [T][B][I]
               const float* __restrict__ hier,   // [B][N]
               const float* __restrict__ h0,     // [B][N]
               const float* __restrict__ W_in,   // [N][I]
               const float* __restrict__ b_in,   // [N]
               const float* __restrict__ W_hh,   // [N][N]
               const float* __restrict__ b_hh,   // [N]
               const float* __restrict__ W_ff,   // [N][N]
               const float* __restrict__ b_ff,   // [N]
               const float* __restrict__ W_fc,   // [2][N]
               const float* __restrict__ b_fc,   // [2]
               float* __restrict__ out)          // [B][2]
{
  // frag store: [parity][global k-slot 0..7][64 lanes][8 bf16] = 16 KiB
  __shared__ __attribute__((aligned(16))) short ldsf[2][8][64][8];
  __shared__ float ldsh[16][264];  // final h scratch (padded)

  const int tid  = threadIdx.x;
  const int wave = tid >> 6;    // 0..7; owns rows [32w,32w+32) = k-slot w
  const int lane = tid & 63;
  const int g    = lane >> 4;   // k-group 0..3
  const int c    = lane & 15;   // batch col (B/C roles) or M-row (A role)
  const int b0   = blockIdx.x * 16;

  const int m0 = 32 * wave + c;   // A-tile row, tile 0
  const int m1 = m0 + 16;         // tile 1

  // LDS indices (short8 units). Own slot: wave. Foreign j -> (wave+j)&7.
  const int wr  = wave * 64 + lane;
  const int rd1 = ((wave + 1) & 7) * 64 + lane;
  const int rd2 = ((wave + 2) & 7) * 64 + lane;
  const int rd3 = ((wave + 3) & 7) * 64 + lane;
  const int rd4 = ((wave + 4) & 7) * 64 + lane;
  const int rd5 = ((wave + 5) & 7) * 64 + lane;
  const int rd6 = ((wave + 6) & 7) * 64 + lane;
  const int rd7 = ((wave + 7) & 7) * 64 + lane;

  // ---- prologue: cst = 0.5*(b_hh + b_in + b_ff + hier @ W_ff^T) via MFMA ----
  f32x4 cst0 = {0.f,0.f,0.f,0.f}, cst1 = {0.f,0.f,0.f,0.f};
  {
    const float* hp = hier + (size_t)(b0 + c) * NDIM + 4 * g;
    const float* w0 = W_ff + (size_t)m0 * NDIM + 4 * g;
    const float* w1 = W_ff + (size_t)m1 * NDIM + 4 * g;
#pragma unroll
    for (int kt = 0; kt < 8; ++kt) {
      short8 bh  = pack2(*(const f32x4*)(hp + kt * 32), *(const f32x4*)(hp + kt * 32 + 16));
      short8 af0 = pack2(*(const f32x4*)(w0 + kt * 32), *(const f32x4*)(w0 + kt * 32 + 16));
      short8 af1 = pack2(*(const f32x4*)(w1 + kt * 32), *(const f32x4*)(w1 + kt * 32 + 16));
      cst0 = MFMA(af0, bh, cst0, 0, 0, 0);
      cst1 = MFMA(af1, bh, cst1, 0, 0, 0);
    }
  }
#pragma unroll
  for (int r = 0; r < 4; ++r) {
    const int n0 = 32 * wave + 4 * g + r;
    cst0[r] = 0.5f * (cst0[r] + b_hh[n0]      + b_in[n0]      + b_ff[n0]);
    cst1[r] = 0.5f * (cst1[r] + b_hh[n0 + 16] + b_in[n0 + 16] + b_ff[n0 + 16]);
  }

  // ---- A-frags: 0.5*W_hh (diag zeroed), k-slots rotated so reg slot j
  //      is global slot (wave+j)&7 (slot 0 = own); 0.5*W_in (I=28 pad 32) ----
  short8 A_hh[2][8];
  short8 A_in[2];
#pragma unroll
  for (int i = 0; i < 2; ++i) {
    const int row = 32 * wave + 16 * i + c;
    const float* wrow = W_hh + (size_t)row * NDIM;
#pragma unroll
    for (int j = 0; j < 8; ++j) {
      const int ktg = (wave + j) & 7;
      f32x4 lo = *(const f32x4*)(wrow + 32 * ktg + 4 * g);
      f32x4 hi = *(const f32x4*)(wrow + 32 * ktg + 16 + 4 * g);
#pragma unroll
      for (int q = 0; q < 4; ++q) {
        const int kl = 32 * ktg + 4 * g + q, kh = kl + 16;
        lo[q] = (kl == row) ? 0.f : 0.5f * lo[q];
        hi[q] = (kh == row) ? 0.f : 0.5f * hi[q];
      }
      A_hh[i][j] = pack2(lo, hi);
    }
    const float* p = W_in + (size_t)row * IDIM;
    f32x4 lo = *(const f32x4*)(p + 4 * g);
    f32x4 hi = {0.f, 0.f, 0.f, 0.f};
    if (g < 3) hi = *(const f32x4*)(p + 16 + 4 * g);  // k rows 28..31 stay 0
#pragma unroll
    for (int q = 0; q < 4; ++q) { lo[q] *= 0.5f; hi[q] *= 0.5f; }
    A_in[i] = pack2(lo, hi);
  }

  // ---- h0: f32 state (C layout) + own bf16 frag into buf 0 ----
  f32x4 hc0, hc1;
  short8 Bown;
  {
    const float* hp = h0 + (size_t)(b0 + c) * NDIM + 32 * wave + 4 * g;
    hc0 = *(const f32x4*)(hp + 0);
    hc1 = *(const f32x4*)(hp + 16);
    Bown = pack2(hc0, hc1);
    ((short8*)(&ldsf[0][0][0][0]))[wr] = Bown;
  }

  // ---- data prefetch t=0..3; branchless hi via per-thread constant offset.
  // g==3's hi reads in-bounds garbage (cols 24..27); annihilated by A zeros.
  const int hiOff = (g < 3) ? 16 : -4;
  const float* dpf = data + (size_t)(b0 + c) * IDIM + 4 * g;
  f32x4 dlo0, dlo1, dlo2, dlo3, dhi0, dhi1, dhi2, dhi3;
  dlo0 = *(const f32x4*)dpf; dhi0 = *(const f32x4*)(dpf + hiOff); dpf += BATCH * IDIM;
  dlo1 = *(const f32x4*)dpf; dhi1 = *(const f32x4*)(dpf + hiOff); dpf += BATCH * IDIM;
  dlo2 = *(const f32x4*)dpf; dhi2 = *(const f32x4*)(dpf + hiOff); dpf += BATCH * IDIM;
  dlo3 = *(const f32x4*)dpf; dhi3 = *(const f32x4*)(dpf + hiOff); dpf += BATCH * IDIM;
  // dpf now points at t=4 (first in-loop prefetch target)

  __syncthreads();  // initial frags visible

  // ---- time loop: 511 full-prefetch groups, then 4 peeled steps (PF=0) ----
  for (int t = 0; t < TSTEPS - 4; t += 4) {
    RNN_STEP(0, dlo0, dhi0, 1)
    RNN_STEP(1, dlo1, dhi1, 1)
    RNN_STEP(0, dlo2, dhi2, 1)
    RNN_STEP(1, dlo3, dhi3, 1)
  }
  RNN_STEP(0, dlo0, dhi0, 0)
  RNN_STEP(1, dlo1, dhi1, 0)
  RNN_STEP(0, dlo2, dhi2, 0)
  RNN_STEP(1, dlo3, dhi3, 0)

  // ---- readout: out = hT @ W_fc^T + b_fc ----
  *(f32x4*)(&ldsh[c][32 * wave + 4 * g])      = hc0;
  *(f32x4*)(&ldsh[c][32 * wave + 16 + 4 * g]) = hc1;
  __syncthreads();
  if (tid < 32) {
    int b = tid >> 1, cls = tid & 1;
    float s = b_fc[cls];
    const float* wf = W_fc + (size_t)cls * NDIM;
#pragma unroll 8
    for (int n = 0; n < NDIM; ++n) s += ldsh[b][n] * wf[n];
    out[(size_t)(b0 + b) * 2 + cls] = s;
  }
}

extern "C" void kernel_launch(void* const* d_in, const int* in_sizes, int n_in,
                              void* d_out, int out_size, void* d_ws, size_t ws_size,
                              hipStream_t stream) {
  const float* data = (const float*)d_in[0];
  const float* hier = (const float*)d_in[1];
  const float* h0   = (const float*)d_in[2];
  const float* W_in = (const float*)d_in[3];
  const float* b_in = (const float*)d_in[4];
  const float* W_hh = (const float*)d_in[5];
  const float* b_hh = (const float*)d_in[6];
  const float* W_ff = (const float*)d_in[7];
  const float* b_ff = (const float*)d_in[8];
  const float* W_fc = (const float*)d_in[9];
  const float* b_fc = (const float*)d_in[10];
  rnn_fused<<<dim3(BATCH / 16), dim3(512), 0, stream>>>(
      data, hier, h0, W_in, b_in, W_hh, b_hh, W_ff, b_ff, W_fc, b_fc,
      (float*)d_out);
}